// Round 4
// baseline (1360.531 us; speedup 1.0000x reference)
//
#include <hip/hip_runtime.h>

// MeanShift round 13 — single persistent kernel, hand-rolled grid barrier
// (NOT cooperative launch; r11's failure used hipLaunchCooperativeKernel +
// cg::sync, which is the prime suspect). 9 dispatches -> 1 kernel + 1 tiny
// memset. All phase bodies are r12-proven text (186.4us, absmax 0.0).
// Gap model (r9->r10->r12): 3.3us/boundary x 8 remaining = ~26us target.
// Barrier: 16-shard arrival counters + master + generation, device-scope
// atomics, s_sleep spin with bounded timeout (fails visibly, never hangs).
// Co-residency: 512 blocks, __launch_bounds__(256,2) => 2 blocks/CU x 256 CU.

#define NPTS   200000
#define DIM    64
#define KC     256
#define BW2    144.0f
#define NW     3125
#define FABLK  782
#define PBLK   1024
#define SUBN   6400
#define SCHUNK 50
#define SNB    (SUBN / SCHUNK)   // 128
#define NKD    (KC * DIM)        // 16384
#define GRID   512
#define NSH    16
#define SHSZ   (GRID / NSH)      // 32
// flags: [0]=MM3, [4..10]=per-iter conv, [15]=NONUNI

struct KParams {
    const float* x;
    const int*   seed;
    float* out;
    float* x2; double* total; double* totpart; float* cseed;
    float* c1; float* c1n; float* c2; float* c2n; float* ccur;
    float* c9; float* c9n; float* c10; float* c10n;
    float* exA; int* cntA; float* exB; int* cntB;
    unsigned* cmaxbits; int* flags; float* pcnts;
    float* dbest1; int* ibest1;
    float* psums; float* dbestK; int* ibestK;  // overlay: disjoint phases
    float* cwn;   // KC+1 floats (j-loop center norms; [KC] = max)
    int* bar;     // [0..NSH-1]=cnt, [NSH]=master, [NSH+1]=gen (memset to 0)
};

__device__ __forceinline__ int aload(int* p) {
    return __hip_atomic_load(p, __ATOMIC_RELAXED, __HIP_MEMORY_SCOPE_AGENT);
}
__device__ __forceinline__ unsigned aloadu(unsigned* p) {
    return __hip_atomic_load(p, __ATOMIC_RELAXED, __HIP_MEMORY_SCOPE_AGENT);
}

// sharded sense barrier; bounded spin so failure is visible, not a hang
__device__ __forceinline__ void gbar(int* bar, int bid, int tid) {
    __syncthreads();
    if (tid == 0) {
        __threadfence();                       // release prior writes
        int* gen = bar + NSH + 1;
        const int g0 = __hip_atomic_load(gen, __ATOMIC_RELAXED, __HIP_MEMORY_SCOPE_AGENT);
        int a = __hip_atomic_fetch_add(bar + (bid & (NSH - 1)), 1,
                                       __ATOMIC_ACQ_REL, __HIP_MEMORY_SCOPE_AGENT);
        if (a == SHSZ - 1) {
            __hip_atomic_store(bar + (bid & (NSH - 1)), 0,
                               __ATOMIC_RELAXED, __HIP_MEMORY_SCOPE_AGENT);
            int m = __hip_atomic_fetch_add(bar + NSH, 1,
                                           __ATOMIC_ACQ_REL, __HIP_MEMORY_SCOPE_AGENT);
            if (m == NSH - 1) {
                __hip_atomic_store(bar + NSH, 0,
                                   __ATOMIC_RELAXED, __HIP_MEMORY_SCOPE_AGENT);
                __hip_atomic_fetch_add(gen, 1,
                                       __ATOMIC_RELEASE, __HIP_MEMORY_SCOPE_AGENT);
            }
        }
        int sp = 0;
        while (__hip_atomic_load(gen, __ATOMIC_ACQUIRE, __HIP_MEMORY_SCOPE_AGENT) == g0 &&
               sp < (1 << 20)) { __builtin_amdgcn_s_sleep(2); ++sp; }
        __threadfence();                       // acquire side
    }
    __syncthreads();
}

// screen + block-cooperative exact resolve (r12 body, tile-strided)
__device__ __forceinline__ void screen_pass(const KParams& prm, const float* cen,
                                            const float* cnorm, unsigned* cmaxslot,
                                            float* exS, int* cntS,
                                            char* shraw, int bid, int tid) {
    float* px = (float*)shraw;
    float* x2sh = (float*)(shraw + 256);
    unsigned long long* wmask = (unsigned long long*)(shraw + 264);
    const float cm = sqrtf(__uint_as_float(aloadu(cmaxslot)));
    const float r = 12.0f - cm - 1e-3f;
    const float thr = (r > 0.f) ? r * r : -1.f;
    for (int tile = bid; tile < FABLK; tile += GRID) {
        const int i = tile * 256 + tid;
        bool susp = (i < NPTS) && (prm.x2[i] >= thr);
        unsigned long long bl = __ballot(susp);
        if ((tid & 63) == 0) wmask[tid >> 6] = bl;
        __syncthreads();
        for (int wv = 0; wv < 4; wv++) {
            unsigned long long m = wmask[wv];
            while (m) {
                const int l = __ffsll(m) - 1;
                m &= m - 1;
                const int pi = tile * 256 + wv * 64 + l;
                __syncthreads();
                if (tid < 16) ((float4*)px)[tid] = ((const float4*)(prm.x + (size_t)pi * DIM))[tid];
                if (tid == 16) x2sh[0] = prm.x2[pi];
                __syncthreads();
                const float* C = cen + tid * DIM;
                float a0 = 0.f, a1 = 0.f, a2 = 0.f, a3 = 0.f;
#pragma unroll
                for (int d = 0; d < DIM; d += 4) {
                    a0 = fmaf(C[d],     px[d],     a0);
                    a1 = fmaf(C[d + 1], px[d + 1], a1);
                    a2 = fmaf(C[d + 2], px[d + 2], a2);
                    a3 = fmaf(C[d + 3], px[d + 3], a3);
                }
                float d2 = x2sh[0] + cnorm[tid] - 2.f * ((a0 + a1) + (a2 + a3));
                if (!(d2 < BW2)) {
                    atomicAdd(&cntS[tid], 1);
#pragma unroll 4
                    for (int d = 0; d < DIM; d++) atomicAdd(&exS[tid * DIM + d], px[d]);
                }
            }
        }
        __syncthreads();   // wmask WAR guard across tiles
    }
}

__global__ __launch_bounds__(256, 2) void fused_kernel(KParams prm) {
    __shared__ __align__(16) char shraw[13056];
    const int bid = blockIdx.x;
    const int tid = threadIdx.x;
    int* bar = prm.bar;

    // ========== P1: prep (x2 + fp64 column partials, 1024 vb) + init ======
    {
        double (*sd)[4] = (double(*)[4])shraw;
        const int sub = tid & 15;
        for (int vb = bid; vb < PBLK; vb += GRID) {
            double a0 = 0.0, a1 = 0.0, a2 = 0.0, a3 = 0.0;
            for (size_t f4 = (size_t)vb * 256 + tid; f4 < (size_t)NPTS * DIM / 4;
                 f4 += (size_t)PBLK * 256) {
                float4 v = ((const float4*)prm.x)[f4];
                a0 += (double)v.x; a1 += (double)v.y; a2 += (double)v.z; a3 += (double)v.w;
                float sq = v.x * v.x + v.y * v.y + v.z * v.z + v.w * v.w;
                sq += __shfl_xor(sq, 1, 64);
                sq += __shfl_xor(sq, 2, 64);
                sq += __shfl_xor(sq, 4, 64);
                sq += __shfl_xor(sq, 8, 64);
                if (sub == 0) prm.x2[f4 >> 4] = sq;
            }
            sd[tid][0] = a0; sd[tid][1] = a1; sd[tid][2] = a2; sd[tid][3] = a3;
            __syncthreads();
            if (tid < 64) {
                const int q = tid >> 2, j = tid & 3;
                double s = 0.0;
                for (int m = 0; m < 16; m++) s += sd[m * 16 + q][j];
                prm.totpart[(size_t)vb * 64 + tid] = s;
            }
            __syncthreads();
        }
        if (bid < 64) {   // fused init (r12 prep init body)
            const int t = bid * 256 + tid;
            const int k = t >> 6, d = t & 63;
            int si = prm.seed[k];
            if ((unsigned)si >= NPTS) si = 0;
            prm.cseed[t] = prm.x[(size_t)si * DIM + d];
            prm.exA[t] = 0.f; prm.exB[t] = 0.f;
            if (t < KC) { prm.cntA[t] = 0; prm.cntB[t] = 0; }
            if (t < 16) { prm.cmaxbits[t] = 0u; prm.flags[t] = 0; }
        }
    }
    gbar(bar, bid, tid);   // 1

    // ========== P2: iter-1 accum (128 blocks) + fp64 grand total =========
    if (bid == SNB) {      // grand-total reduce (r12 body)
        double* sdt = (double*)shraw;
        const int q = tid >> 6, d2 = tid & 63;
        double s = 0.0;
#pragma unroll 8
        for (int b = q * (PBLK / 4); b < (q + 1) * (PBLK / 4); b++)
            s += prm.totpart[(size_t)b * 64 + d2];
        sdt[tid] = s;
        __syncthreads();
        if (tid < 64)
            prm.total[tid] = sdt[tid] + sdt[tid + 64] + sdt[tid + 128] + sdt[tid + 192];
    } else if (bid < SNB) {   // accum chunk (r12 body)
        float* xs  = (float*)shraw;
        float* x2s = (float*)(shraw + SCHUNK * DIM * 4);
        const int k = tid;
        const int base = bid * SCHUNK;
        float c[DIM];
#pragma unroll
        for (int d = 0; d < DIM; d += 4) {
            float4 v = *(const float4*)(prm.cseed + k * DIM + d);
            c[d] = v.x; c[d + 1] = v.y; c[d + 2] = v.z; c[d + 3] = v.w;
        }
        float c2 = 0.f;
#pragma unroll
        for (int d = 0; d < DIM; d++) c2 += c[d] * c[d];
        float sum[DIM], P[DIM];
#pragma unroll
        for (int d = 0; d < DIM; d++) { sum[d] = 0.f; P[d] = 0.f; }
        float cnt = 0.f, mp = 0.f;
        for (int t = tid; t < SCHUNK * DIM / 4; t += 256)
            ((float4*)xs)[t] = ((const float4*)(prm.x + (size_t)base * DIM))[t];
        for (int t = tid; t < SCHUNK; t += 256) x2s[t] = prm.x2[base + t];
        __syncthreads();
        for (int i = 0; i < SCHUNK; i++) {
            const float4* xi = (const float4*)(xs + i * DIM);
            float a0 = 0.f, a1 = 0.f, a2 = 0.f, a3 = 0.f;
#pragma unroll
            for (int q = 0; q < 16; q++) {
                float4 v = xi[q];
                sum[4 * q]     += mp * P[4 * q];
                sum[4 * q + 1] += mp * P[4 * q + 1];
                sum[4 * q + 2] += mp * P[4 * q + 2];
                sum[4 * q + 3] += mp * P[4 * q + 3];
                P[4 * q] = v.x; P[4 * q + 1] = v.y;
                P[4 * q + 2] = v.z; P[4 * q + 3] = v.w;
                a0 += c[4 * q] * v.x;     a1 += c[4 * q + 1] * v.y;
                a2 += c[4 * q + 2] * v.z; a3 += c[4 * q + 3] * v.w;
            }
            float dist2 = c2 + x2s[i] - 2.f * ((a0 + a1) + (a2 + a3));
            mp = (dist2 < BW2) ? 1.f : 0.f;
            cnt += mp;
        }
#pragma unroll
        for (int d = 0; d < DIM; d++) sum[d] += mp * P[d];
        float* ps = prm.psums + (size_t)bid * NKD + k * DIM;
#pragma unroll
        for (int d = 0; d < DIM; d += 4) {
            float4 v = { sum[d], sum[d + 1], sum[d + 2], sum[d + 3] };
            *(float4*)(ps + d) = v;
        }
        prm.pcnts[bid * KC + k] = cnt;
    }
    gbar(bar, bid, tid);   // 2

    // ========== P3: c1 from 128 partials (r12 upd1 body) ==================
    if (bid < 64) {
        const int kd = bid * 256 + tid;
        const int k = kd >> 6, d = kd & 63;
        float s = 0.f;
#pragma unroll 8
        for (int b = 0; b < SNB; b++) s += prm.psums[(size_t)b * NKD + kd];
        float cn = 0.f;
        for (int b = d; b < SNB; b += 64) cn += prm.pcnts[b * KC + k];
#pragma unroll
        for (int off = 32; off > 0; off >>= 1) cn += __shfl_xor(cn, off, 64);
        float c = s / cn;
        prm.c1[kd] = c;
        float q = c * c;
#pragma unroll
        for (int off = 32; off > 0; off >>= 1) q += __shfl_xor(q, off, 64);
        if (d == 0) { prm.c1n[k] = q; atomicMax(prm.cmaxbits + 1, __float_as_uint(q)); }
    }
    gbar(bar, bid, tid);   // 3

    // ========== P4: iteration 2 screen -> setA ============================
    screen_pass(prm, prm.c1, prm.c1n, prm.cmaxbits + 1, prm.exA, prm.cntA, shraw, bid, tid);
    gbar(bar, bid, tid);   // 4

    // ========== P5: c2 from setA (r12 update2 body) =======================
    if (bid < 64) {
        const int kd = bid * 256 + tid;
        const int k = kd >> 6, d = kd & 63;
        const float ex = prm.exA[kd];
        const int cn = prm.cntA[k];
        const float cnew = (float)((prm.total[d] - (double)ex) / (double)(NPTS - cn));
        prm.c2[kd] = cnew;
        float q = cnew * cnew;
#pragma unroll
        for (int off = 32; off > 0; off >>= 1) q += __shfl_xor(q, off, 64);
        if (d == 0) { prm.c2n[k] = q; atomicMax(prm.cmaxbits + 2, __float_as_uint(q)); }
    }
    gbar(bar, bid, tid);   // 5

    // ========== P6: iteration 3 screen -> setB ============================
    screen_pass(prm, prm.c2, prm.c2n, prm.cmaxbits + 2, prm.exB, prm.cntB, shraw, bid, tid);
    gbar(bar, bid, tid);   // 6

    // ========== P7: update3: c3 -> ccur, MM3 flag, cmax3 ==================
    if (bid < 64) {
        const int kd = bid * 256 + tid;
        const int k = kd >> 6, d = kd & 63;
        const float ex = prm.exB[kd];
        const int cn = prm.cntB[k];
        const float cnew = (float)((prm.total[d] - (double)ex) / (double)(NPTS - cn));
        prm.ccur[kd] = cnew;
        float q = cnew * cnew;
#pragma unroll
        for (int off = 32; off > 0; off >>= 1) q += __shfl_xor(q, off, 64);
        if (d == 0) atomicMax(prm.cmaxbits + 3, __float_as_uint(q));
        bool same = (__float_as_uint(cnew) == __float_as_uint(prm.c2[kd]));
        unsigned long long bl = __ballot(!same);
        if (d == 0 && (bl != 0ull || cn != 0)) atomicOr(&prm.flags[0], 1);
    }
    gbar(bar, bid, tid);   // 7

    // ========== P8: iterations 4..10 (grid-parallel, r12 math) ============
    const int mm3 = aload(&prm.flags[0]);
    bool broke = false;
    if (mm3 != 0) {
        for (int j = 4; j <= 10; j++) {
            // zero accumulators; per-center serial norms + max (block 64)
            if (bid < 64) prm.exA[bid * 256 + tid] = 0.f;
            if (bid == 65) prm.cntA[tid] = 0;
            if (bid == 64) {
                float* tmp = (float*)shraw;
                float nn = 0.f;
                for (int d = 0; d < DIM; d++) {
                    float v = prm.ccur[tid * DIM + d];
                    nn = fmaf(v, v, nn);
                }
                prm.cwn[tid] = nn; tmp[tid] = nn;
                __syncthreads();
                if (tid == 0) {
                    float mx = 0.f;
                    for (int k2 = 0; k2 < KC; k2++) mx = fmaxf(mx, tmp[k2]);
                    prm.cwn[KC] = mx;
                }
            }
            gbar(bar, bid, tid);
            // screen + exact resolve, grid-stride (r12 tail inner math)
            {
                float* cwn_l = (float*)shraw;
                cwn_l[tid] = prm.cwn[tid];
                __syncthreads();
                const float cmaxv = (j == 4) ? __uint_as_float(aloadu(prm.cmaxbits + 3))
                                             : prm.cwn[KC];
                const float cm = sqrtf(cmaxv);
                const float r = 12.0f - cm - 1e-3f;
                const float thr = (r > 0.f) ? r * r : -1.f;
                for (int i = bid * 256 + tid; i < NPTS; i += GRID * 256) {
                    const float xv = prm.x2[i];
                    if (xv >= thr) {
                        float px[DIM];
                        const float4* xr = (const float4*)(prm.x + (size_t)i * DIM);
#pragma unroll
                        for (int q = 0; q < 16; q++) {
                            float4 v = xr[q];
                            px[4 * q] = v.x; px[4 * q + 1] = v.y;
                            px[4 * q + 2] = v.z; px[4 * q + 3] = v.w;
                        }
                        for (int k2 = 0; k2 < KC; k2++) {
                            const float* C = prm.ccur + k2 * DIM;
                            float a0 = 0.f, a1 = 0.f, a2 = 0.f, a3 = 0.f;
#pragma unroll
                            for (int d = 0; d < DIM; d += 4) {
                                a0 = fmaf(C[d],     px[d],     a0);
                                a1 = fmaf(C[d + 1], px[d + 1], a1);
                                a2 = fmaf(C[d + 2], px[d + 2], a2);
                                a3 = fmaf(C[d + 3], px[d + 3], a3);
                            }
                            float d2 = xv + cwn_l[k2] - 2.f * ((a0 + a1) + (a2 + a3));
                            if (!(d2 < BW2)) {
                                atomicAdd(&prm.cntA[k2], 1);
#pragma unroll 4
                                for (int d = 0; d < DIM; d++)
                                    atomicAdd(&prm.exA[k2 * DIM + d], px[d]);
                            }
                        }
                    }
                }
            }
            gbar(bar, bid, tid);
            // update + bitwise convergence flag
            if (bid < 64) {
                const int t = bid * 256 + tid;
                const int k2 = t >> 6, dd = t & 63;
                const float ex = prm.exA[t];
                const int cn = prm.cntA[k2];
                const float cnew = (float)((prm.total[dd] - (double)ex) / (double)(NPTS - cn));
                const int lc = (__float_as_uint(cnew) == __float_as_uint(prm.ccur[t]));
                prm.ccur[t] = cnew;
                if (j == 9)  prm.c9[t]  = cnew;
                if (j == 10) prm.c10[t] = cnew;
                unsigned long long bl = __ballot(lc == 0);
                if ((tid & 63) == 0 && bl != 0ull) atomicOr(&prm.flags[j], 1);
            }
            gbar(bar, bid, tid);
            if (aload(&prm.flags[j]) == 0) { broke = true; break; }
        }
    }

    // ========== P9: finalize c9/c10, NONUNI flag, norms (block-local) =====
    if (bid < 64) {
        const int t = bid * 256 + tid;
        float v9, v10;
        if (mm3 != 0 && !broke) { v9 = prm.c9[t]; v10 = prm.c10[t]; }
        else { const float v = prm.ccur[t]; prm.c9[t] = v; prm.c10[t] = v; v9 = v; v10 = v; }
        const int dd = t & 63;
        const float mf = (float)(prm.total[dd] / (double)NPTS);
        const int localuni = (__float_as_uint(v9) == __float_as_uint(mf)) &&
                             (__float_as_uint(v10) == __float_as_uint(mf));
        unsigned long long blu = __ballot(localuni == 0);
        if ((tid & 63) == 0 && blu != 0ull) atomicOr(&prm.flags[15], 1);
        __syncthreads();
        if (tid < 4) {   // serial per-center norms (r12 order)
            const int k = bid * 4 + tid;
            float n9 = 0.f, n10 = 0.f;
            for (int d = 0; d < DIM; d++) {
                float a = prm.c9[k * DIM + d];  n9  = fmaf(a, a, n9);
                float b = prm.c10[k * DIM + d]; n10 = fmaf(b, b, n10);
            }
            prm.c9n[k] = n9; prm.c10n[k] = n10;
        }
    }
    gbar(bar, bid, tid);   // 8

    // ========== P10: final3 + final_exact (r12 bodies, tile-strided) ======
    {
        float* s9  = (float*)shraw;
        float* s10 = (float*)(shraw + 256);
        float* sc  = (float*)(shraw + 512);
        if (tid < 64) s9[tid] = prm.c9[tid];
        else if (tid < 128) s10[tid - 64] = prm.c10[tid - 64];
        __syncthreads();
        if (tid < 64) {
            float v = s9[tid]; float q = v * v;
#pragma unroll
            for (int off = 32; off > 0; off >>= 1) q += __shfl_xor(q, off, 64);
            if (tid == 0) sc[0] = q;
        } else if (tid < 128) {
            float v = s10[tid - 64]; float q = v * v;
#pragma unroll
            for (int off = 32; off > 0; off >>= 1) q += __shfl_xor(q, off, 64);
            if (tid == 64) sc[1] = q;
        }
        __syncthreads();
        for (int tile = bid; tile < FABLK; tile += GRID) {
            const int i = tile * 256 + tid;
            const bool valid = (i < NPTS);
            const int ii = valid ? i : 0;
            const float4* xr = (const float4*)(prm.x + (size_t)ii * DIM);
            float a0 = 0.f, a1 = 0.f, a2 = 0.f, a3 = 0.f;
            float b0 = 0.f, b1 = 0.f, b2 = 0.f, b3 = 0.f;
#pragma unroll
            for (int q = 0; q < 16; q++) {
                float4 v = xr[q];
                float4 u9  = ((const float4*)s9)[q];
                float4 u10 = ((const float4*)s10)[q];
                a0 = fmaf(u9.x, v.x, a0);  a1 = fmaf(u9.y, v.y, a1);
                a2 = fmaf(u9.z, v.z, a2);  a3 = fmaf(u9.w, v.w, a3);
                b0 = fmaf(u10.x, v.x, b0); b1 = fmaf(u10.y, v.y, b1);
                b2 = fmaf(u10.z, v.z, b2); b3 = fmaf(u10.w, v.w, b3);
            }
            const float x2v = prm.x2[ii];
            float d9 = x2v + sc[0] - 2.f * ((a0 + a1) + (a2 + a3));
            float dd = fmaxf(x2v + sc[1] - 2.f * ((b0 + b1) + (b2 + b3)), 0.f);
            float cand = (valid && d9 < BW2) ? dd : INFINITY;
            float m = cand;
#pragma unroll
            for (int off = 32; off > 0; off >>= 1) m = fminf(m, __shfl_xor(m, off, 64));
            unsigned long long bl = __ballot(cand == m);
            int sl = __ffsll(bl) - 1;
            int gi = (tile * 256 + (tid & ~63)) + sl;
            const int gw = tile * 4 + (tid >> 6);
            if (gw < NW && (tid & 63) == 0) { prm.dbest1[gw] = m; prm.ibest1[gw] = gi; }
        }
        if (aload(&prm.flags[15]) != 0) {   // non-uniform only
            for (int tile = bid; tile < FABLK; tile += GRID) {
                const int wave = tile * 4 + (tid >> 6);
                if (wave >= NW) continue;
                const int lane = tid & 63;
                const int idx = wave * 64 + lane;
                float px[DIM];
                const float4* xr = (const float4*)(prm.x + (size_t)idx * DIM);
#pragma unroll
                for (int q = 0; q < 16; q++) {
                    float4 v = xr[q];
                    px[4 * q] = v.x; px[4 * q + 1] = v.y;
                    px[4 * q + 2] = v.z; px[4 * q + 3] = v.w;
                }
                const float x2v = prm.x2[idx];
                float db[4];
                int   ib[4];
                for (int k = 0; k < KC; k++) {
                    const float* A = prm.c9  + k * DIM;
                    const float* B = prm.c10 + k * DIM;
                    float a0 = 0.f, a1 = 0.f, a2 = 0.f, a3 = 0.f;
                    float b0 = 0.f, b1 = 0.f, b2 = 0.f, b3 = 0.f;
#pragma unroll
                    for (int d = 0; d < DIM; d += 4) {
                        a0 = fmaf(A[d],     px[d],     a0);
                        a1 = fmaf(A[d + 1], px[d + 1], a1);
                        a2 = fmaf(A[d + 2], px[d + 2], a2);
                        a3 = fmaf(A[d + 3], px[d + 3], a3);
                        b0 = fmaf(B[d],     px[d],     b0);
                        b1 = fmaf(B[d + 1], px[d + 1], b1);
                        b2 = fmaf(B[d + 2], px[d + 2], b2);
                        b3 = fmaf(B[d + 3], px[d + 3], b3);
                    }
                    float d9 = x2v + prm.c9n[k] - 2.f * ((a0 + a1) + (a2 + a3));
                    float dd2 = x2v + prm.c10n[k] - 2.f * ((b0 + b1) + (b2 + b3));
                    dd2 = fmaxf(dd2, 0.f);
                    float cand = (d9 < BW2) ? dd2 : INFINITY;
                    float m = cand;
#pragma unroll
                    for (int off = 32; off > 0; off >>= 1) m = fminf(m, __shfl_xor(m, off, 64));
                    unsigned long long bl = __ballot(cand == m);
                    int sl = __ffsll(bl) - 1;
                    int gi = wave * 64 + sl;
                    int qq = k >> 6;
                    if ((k & 63) == lane) { db[qq] = m; ib[qq] = gi; }
                }
#pragma unroll
                for (int q = 0; q < 4; q++) {
                    prm.dbestK[(size_t)wave * KC + q * 64 + lane] = db[q];
                    prm.ibestK[(size_t)wave * KC + q * 64 + lane] = ib[q];
                }
            }
        }
    }
    gbar(bar, bid, tid);   // 9

    // ========== P11: combine (r12 body; single writer of out) =============
    if (bid < KC) {
        float* sdc = (float*)shraw;
        int*   sic = (int*)(shraw + 1024);
        const int k = bid;
        const int t = tid;
        const bool uni = (aload(&prm.flags[15]) == 0);
        float bd = INFINITY;
        int   bi = 0x7FFFFFFF;
        if (uni) {
            for (int w = t; w < NW; w += 256) {
                float d = prm.dbest1[w];
                int   i = prm.ibest1[w];
                if (d < bd || (d == bd && i < bi)) { bd = d; bi = i; }
            }
        } else {
            for (int w = t; w < NW; w += 256) {
                float d = prm.dbestK[(size_t)w * KC + k];
                int   i = prm.ibestK[(size_t)w * KC + k];
                if (d < bd || (d == bd && i < bi)) { bd = d; bi = i; }
            }
        }
        sdc[t] = bd; sic[t] = bi;
        __syncthreads();
        for (int s = 128; s > 0; s >>= 1) {
            if (t < s) {
                float d = sdc[t + s]; int i = sic[t + s];
                if (d < sdc[t] || (d == sdc[t] && i < sic[t])) { sdc[t] = d; sic[t] = i; }
            }
            __syncthreads();
        }
        bi = sic[0];
        if ((unsigned)bi >= NPTS) bi = 0;
        if (t < DIM) {
            prm.out[k * DIM + t] = prm.c10[k * DIM + t];
            prm.out[KC * DIM + k * DIM + t] = prm.x[(size_t)bi * DIM + t];
        }
        if (t == 0) prm.out[2 * KC * DIM + k] = (float)bi;
    }
}

extern "C" void kernel_launch(void* const* d_in, const int* in_sizes, int n_in,
                              void* d_out, int out_size, void* d_ws, size_t ws_size,
                              hipStream_t stream) {
    KParams prm;
    prm.x    = (const float*)d_in[0];
    prm.seed = (const int*)d_in[1];
    prm.out  = (float*)d_out;

    char* w = (char*)d_ws;
    auto take = [&](size_t bytes) { char* p = w; w += (bytes + 511) & ~(size_t)511; return p; };
    prm.x2      = (float*)take((size_t)NPTS * 4);
    prm.total   = (double*)take((size_t)DIM * 8);
    prm.totpart = (double*)take((size_t)PBLK * 64 * 8);
    prm.cseed   = (float*)take((size_t)NKD * 4);
    prm.c1      = (float*)take((size_t)NKD * 4);
    prm.c1n     = (float*)take((size_t)KC * 4);
    prm.c2      = (float*)take((size_t)NKD * 4);
    prm.c2n     = (float*)take((size_t)KC * 4);
    prm.ccur    = (float*)take((size_t)NKD * 4);
    prm.c9      = (float*)take((size_t)NKD * 4);
    prm.c9n     = (float*)take((size_t)KC * 4);
    prm.c10     = (float*)take((size_t)NKD * 4);
    prm.c10n    = (float*)take((size_t)KC * 4);
    prm.exA     = (float*)take((size_t)NKD * 4);
    prm.cntA    = (int*)take((size_t)KC * 4);
    prm.exB     = (float*)take((size_t)NKD * 4);
    prm.cntB    = (int*)take((size_t)KC * 4);
    prm.cmaxbits = (unsigned*)take((size_t)16 * 4);
    prm.flags   = (int*)take((size_t)16 * 4);
    prm.pcnts   = (float*)take((size_t)SNB * KC * 4);
    prm.dbest1  = (float*)take((size_t)NW * 4);
    prm.ibest1  = (int*)take((size_t)NW * 4);
    prm.cwn     = (float*)take((size_t)(KC + 1) * 4);
    prm.bar     = (int*)take((size_t)128);
    // overlay (proven): psums (iter-1, 8.4MB) shares tail region with
    // dbestK/ibestK (final phase) — disjoint phases, ordered by barriers.
    prm.psums  = (float*)w;
    prm.dbestK = (float*)w;
    prm.ibestK = (int*)(w + (((size_t)NW * KC * 4 + 511) & ~(size_t)511));

    hipMemsetAsync(prm.bar, 0, 128, stream);   // barrier state must start 0
    fused_kernel<<<GRID, 256, 0, stream>>>(prm);
}